// Round 7
// baseline (318.551 us; speedup 1.0000x reference)
//
#include <hip/hip_runtime.h>
#include <math.h>

// ---------------------------------------------------------------------------
// TemporalGCN: 2-layer LSTM (per-node sequences) -> 2 GCN rounds -> edge MLP.
//
// R6 post-mortem: in EVERY round so far the compiler re-fetched the 64-float
// Whh row from L1/L2 each timestep (VGPR_Count 48..52 proves no residency);
// ~1.2 GB of L2 weight traffic/layer ~= the stubborn 44-65 us. R7 levers:
//  (a) S=4 sequences/block (grid 400): weight fetch amortized 4x even if
//      reloads persist; occupancy stays healthy.
//  (b) volatile scalar weight loads into wreg[64] (+launch_bounds(256,2)):
//      volatile cannot be duplicated -> compiler must keep values live.
//      VGPR_Count >= ~100 in the profile = the pin worked.
// FP accumulation order identical to R4/R6 (absmax 0.0 preserved).
// ---------------------------------------------------------------------------

#define Hd   64
#define Ed   5
#define Fd   6
#define Bd   8
#define Wd   12
#define Nd   200
#define NSEQ (Bd*Nd)        // 1600 sequences (b,n)
#define NG   (4*Hd)         // 256 gate rows
#define NEDGE (Bd*Nd*Nd)    // 320000 edges
#define SEQB 4              // sequences per LSTM block
#define LNEPS 1e-5f

__device__ __forceinline__ float sigm(float x) { return 1.0f / (1.0f + __expf(-x)); }
__device__ __forceinline__ float tanh_fast(float x) {
  float ax = fabsf(x);
  float t  = __expf(-2.0f * ax);
  float r  = (1.0f - t) / (1.0f + t);
  return copysignf(r, x);
}

// --------------------------------------------------------------------------
// Transpose Wih1 (256x64) -> Wt1 (64x256) so xproj1 can do contiguous
// scalar loads of a k-row.
__global__ __launch_bounds__(256) void k_prep(const float* __restrict__ Wih1,
                                              float* __restrict__ Wt1) {
  int k = blockIdx.x;          // 0..63
  int j = threadIdx.x;         // 0..255
  Wt1[k * NG + j] = Wih1[j * Hd + k];
}

// --------------------------------------------------------------------------
// LSTM layer 0. 400 blocks x 256 threads; block owns SEQB=4 sequences.
// Thread j = gate row j; 64 weights held via VOLATILE loads (no dup/remat).
// Phase A: gates for 4 seqs (weights reused 4x). Phase B: thread (s,u)
// updates c/h for pair (s = tid>>6, u = tid&63). Two barriers/step (R4-
// proven). All accumulation orders bit-identical to R4/R6.
__global__ __launch_bounds__(256, 2) void k_lstm0(
    const float* __restrict__ nf,                       // (B,W,N,F)
    const float* __restrict__ Wih0, const float* __restrict__ Whh0,
    const float* __restrict__ bih0, const float* __restrict__ bhh0,
    float* __restrict__ y0)                             // (NSEQ, W, H)
{
  __shared__ float x_sh[SEQB * Wd * Fd];   // 288
  __shared__ float h_sh[SEQB][Hd];         // 256
  __shared__ float gate_sh[SEQB][NG];      // 1024

  const int tid  = threadIdx.x;
  const int seq0 = blockIdx.x * SEQB;

  for (int idx = tid; idx < SEQB * Wd * Fd; idx += 256) {
    int s = idx / (Wd * Fd); int rem = idx % (Wd * Fd);
    int t = rem / Fd;        int f   = rem % Fd;
    int seq = seq0 + s; int b = seq / Nd; int n = seq % Nd;
    x_sh[idx] = nf[((b * Wd + t) * Nd + n) * Fd + f];
  }
  if (tid < SEQB * Hd) h_sh[tid >> 6][tid & 63] = 0.f;

  const int j = tid;
  // Volatile loads: compiler may not duplicate/rematerialize -> values must
  // stay live in registers across the whole t-loop.
  float wreg[Hd];
  {
    const volatile float* wp = Whh0 + j * Hd;
    #pragma unroll
    for (int k = 0; k < Hd; ++k) wreg[k] = wp[k];
  }
  float wx[Fd];
  {
    const volatile float* xp = Wih0 + j * Fd;
    #pragma unroll
    for (int f = 0; f < Fd; ++f) wx[f] = xp[f];
  }
  const float bias = bih0[j] + bhh0[j];
  const int jt = j >> 6;                 // 0=i,1=f,2=g,3=o (wave-uniform)

  const int su = tid >> 6;               // Phase-B pair: seq index
  const int uu = tid & 63;               //               unit index
  float c = 0.f;                         // cell state for (su,uu)
  __syncthreads();

  for (int t = 0; t < Wd; ++t) {
    // Phase A: 256 gate rows x 4 seqs, activation applied here.
    #pragma unroll
    for (int s = 0; s < SEQB; ++s) {
      const float* xp = x_sh + (s * Wd + t) * Fd;
      float a0 = bias, a1 = 0.f, a2 = 0.f, a3 = 0.f;
      #pragma unroll
      for (int f = 0; f < Fd; ++f) a1 += xp[f] * wx[f];
      const float4* h4 = (const float4*)h_sh[s];
      #pragma unroll
      for (int q = 0; q < 16; ++q) {
        float4 hv = h4[q];
        float d = hv.x * wreg[4 * q]     + hv.y * wreg[4 * q + 1] +
                  hv.z * wreg[4 * q + 2] + hv.w * wreg[4 * q + 3];
        if ((q & 3) == 0) a0 += d; else if ((q & 3) == 1) a1 += d;
        else if ((q & 3) == 2) a2 += d; else a3 += d;
      }
      float acc = (a0 + a1) + (a2 + a3);
      gate_sh[s][j] = (jt == 2) ? tanh_fast(acc) : sigm(acc);
    }
    __syncthreads();
    // Phase B: c/h update; thread owns exactly one (s,u) pair.
    {
      float iv = gate_sh[su][uu];
      float fv = gate_sh[su][64 + uu];
      float gv = gate_sh[su][128 + uu];
      float ov = gate_sh[su][192 + uu];
      c = fv * c + iv * gv;
      float h = ov * tanh_fast(c);
      h_sh[su][uu] = h;
      y0[(seq0 + su) * (Wd * Hd) + t * Hd + uu] = h;
    }
    __syncthreads();
  }
}

// --------------------------------------------------------------------------
// G1 = y0 @ Wih1.T + (bih1+bhh1): (19200 x 64) @ (64 x 256).
// 300 blocks x 256 thr; lane = row, wave = 64-col slab (wave-uniform cols ->
// weights via SCALAR loads; VALU-bound). Output transposed through a 2-tile
// osh in two passes (LDS total 49.9 KB < 64 KB static limit).
__global__ __launch_bounds__(256) void k_xproj1(
    const float* __restrict__ y0,    // rows = seq*12+t
    const float* __restrict__ Wt1,   // (64,256) transposed Wih1
    const float* __restrict__ bih1, const float* __restrict__ bhh1,
    float* __restrict__ G1)          // (19200, 256)
{
  __shared__ float ysh[64 * 65];        // [r][k] pad-65: conflict-free
  __shared__ float osh[2 * 64 * 65];    // two 64x64 out tiles, pad-65

  const int tid  = threadIdx.x;
  const int row0 = blockIdx.x * 64;
  for (int idx = tid; idx < 64 * 64; idx += 256) {
    int r = idx >> 6, k = idx & 63;
    ysh[r * 65 + k] = y0[(row0 + r) * Hd + k];
  }
  __syncthreads();

  const int w = __builtin_amdgcn_readfirstlane(tid >> 6);  // force uniform
  const int r = tid & 63;
  float acc[64];
  #pragma unroll
  for (int c = 0; c < 64; ++c) acc[c] = 0.f;

  const float* wbase = Wt1 + (w << 6);
  #pragma unroll 2
  for (int k = 0; k < 64; ++k) {
    float yv = ysh[r * 65 + k];
    const float* wk = wbase + k * NG;    // uniform address -> s_load
    #pragma unroll
    for (int c = 0; c < 64; ++c) acc[c] = fmaf(yv, wk[c], acc[c]);
  }
  #pragma unroll
  for (int c = 0; c < 64; ++c) acc[c] += bih1[(w << 6) + c] + bhh1[(w << 6) + c];

  // Two passes: waves {0,1} then {2,3} dump 64x64 tiles; everyone stores.
  #pragma unroll
  for (int p = 0; p < 2; ++p) {
    __syncthreads();
    if ((w >> 1) == p) {
      float* orow = osh + ((w & 1) * 64 + r) * 65;
      #pragma unroll
      for (int c = 0; c < 64; ++c) orow[c] = acc[c];  // stride-65: no conflict
    }
    __syncthreads();
    for (int idx = tid; idx < 2 * 64 * 64; idx += 256) {
      int c  = idx & 127;              // col within this 128-col slab
      int rr = idx >> 7;               // row 0..63
      G1[(row0 + rr) * NG + p * 128 + c] =
          osh[((c >> 6) * 64 + rr) * 65 + (c & 63)];   // lanes stride-1: free
    }
  }
}

// --------------------------------------------------------------------------
// LSTM layer 1 recurrence (K=64; input proj precomputed in G1). 400 blocks
// x 256 threads, SEQB=4, same structure as k_lstm0; volatile-pinned weights;
// G1 rows prefetched one timestep ahead (coalesced dword per (s,j)).
__global__ __launch_bounds__(256, 2) void k_lstm1(
    const float* __restrict__ G1,
    const float* __restrict__ Whh1,
    float* __restrict__ hout)        // (NSEQ, H)
{
  __shared__ float h_sh[SEQB][Hd];
  __shared__ float gate_sh[SEQB][NG];

  const int tid  = threadIdx.x;
  const int seq0 = blockIdx.x * SEQB;
  if (tid < SEQB * Hd) h_sh[tid >> 6][tid & 63] = 0.f;

  const int j = tid;
  float wreg[Hd];
  {
    const volatile float* wp = Whh1 + j * Hd;
    #pragma unroll
    for (int k = 0; k < Hd; ++k) wreg[k] = wp[k];
  }
  const int jt = j >> 6;
  const int su = tid >> 6;
  const int uu = tid & 63;
  float c = 0.f;

  float gc[SEQB];
  #pragma unroll
  for (int s = 0; s < SEQB; ++s)
    gc[s] = G1[((seq0 + s) * Wd + 0) * NG + j];   // prefetch t=0
  __syncthreads();

  for (int t = 0; t < Wd; ++t) {
    float gn[SEQB];
    #pragma unroll
    for (int s = 0; s < SEQB; ++s)
      gn[s] = (t + 1 < Wd) ? G1[((seq0 + s) * Wd + t + 1) * NG + j] : 0.f;

    #pragma unroll
    for (int s = 0; s < SEQB; ++s) {
      float a0 = gc[s];                          // bias folded into G1
      float a1 = 0.f, a2 = 0.f, a3 = 0.f;
      const float4* h4 = (const float4*)h_sh[s];
      #pragma unroll
      for (int q = 0; q < 16; ++q) {
        float4 hv = h4[q];
        float d = hv.x * wreg[4 * q]     + hv.y * wreg[4 * q + 1] +
                  hv.z * wreg[4 * q + 2] + hv.w * wreg[4 * q + 3];
        if ((q & 3) == 0) a0 += d; else if ((q & 3) == 1) a1 += d;
        else if ((q & 3) == 2) a2 += d; else a3 += d;
      }
      float acc = (a0 + a1) + (a2 + a3);
      gate_sh[s][j] = (jt == 2) ? tanh_fast(acc) : sigm(acc);
    }
    __syncthreads();
    {
      float iv = gate_sh[su][uu];
      float fv = gate_sh[su][64 + uu];
      float gv = gate_sh[su][128 + uu];
      float ov = gate_sh[su][192 + uu];
      c = fv * c + iv * gv;
      float h = ov * tanh_fast(c);
      h_sh[su][uu] = h;
      if (t == Wd - 1) hout[(seq0 + su) * Hd + uu] = h;
    }
    __syncthreads();
    #pragma unroll
    for (int s = 0; s < SEQB; ++s) gc[s] = gn[s];
  }
}

// --------------------------------------------------------------------------
// Fused per-row node pipeline: wsum (adj x edge reduce over j) -> GCN round 0
// -> GCN round 1 -> u/v precompute for the edge MLP. One block per row
// (b,i); 256 threads. All arithmetic orders identical to the unfused R4
// kernels (wsum via wave shuffle + 4-way combine; LN via shfl_xor).
__global__ __launch_bounds__(256) void k_node(
    const float* __restrict__ ef,    const float* __restrict__ adj,
    const float* __restrict__ h0,
    const float* __restrict__ gcn_W, const float* __restrict__ gcn_b,
    const float* __restrict__ ep_W,  const float* __restrict__ ep_b,
    const float* __restrict__ ln_g,  const float* __restrict__ ln_b,
    const float* __restrict__ W1,    const float* __restrict__ b1,
    float* __restrict__ uu, float* __restrict__ vt)
{
  __shared__ float red[4][6];
  __shared__ float w6[6];
  __shared__ float hcur[Hd];

  const int row = blockIdx.x;      // b*200+i
  const int b = row / Nd, i = row % Nd;
  const int tid = threadIdx.x;

  // ---- wsum: p[e] = sum_j adj*edge[e], p[5] = sum_j adj
  float p[6] = {0.f, 0.f, 0.f, 0.f, 0.f, 0.f};
  if (tid < Nd) {
    float a = adj[(b * Nd + i) * Nd + tid];
    const float* e = ef + (((b * Wd + (Wd - 1)) * Nd + i) * Nd + tid) * Ed;
    p[5] = a;
    #pragma unroll
    for (int k = 0; k < Ed; ++k) p[k] = a * e[k];
  }
  #pragma unroll
  for (int k = 0; k < 6; ++k) {
    float v = p[k];
    for (int off = 32; off > 0; off >>= 1) v += __shfl_down(v, off);
    p[k] = v;
  }
  if ((tid & 63) == 0) {
    #pragma unroll
    for (int k = 0; k < 6; ++k) red[tid >> 6][k] = p[k];
  }
  __syncthreads();
  if (tid < 6)
    w6[tid] = red[0][tid] + red[1][tid] + red[2][tid] + red[3][tid];
  if (tid < Hd) hcur[tid] = h0[row * Hd + tid];
  __syncthreads();

  // ---- 2 GCN rounds (wave 0 only; LN shuffles span exactly 64 lanes)
  const int u = tid & 63;
  #pragma unroll
  for (int round = 0; round < 2; ++round) {
    float hnew = 0.f;
    if (tid < 64) {
      const float* gw = gcn_W + (round * Hd + u) * Hd;
      const float* ew = ep_W  + (round * Hd + u) * Ed;
      float acc = gcn_b[round * Hd + u] + w6[5] * ep_b[round * Hd + u];
      #pragma unroll
      for (int e = 0; e < Ed; ++e) acc += w6[e] * ew[e];
      #pragma unroll 8
      for (int k = 0; k < Hd; ++k) acc += hcur[k] * gw[k];

      float mu = acc;
      #pragma unroll
      for (int off = 1; off < 64; off <<= 1) mu += __shfl_xor(mu, off);
      mu *= (1.f / 64.f);
      float d = acc - mu;
      float var = d * d;
      #pragma unroll
      for (int off = 1; off < 64; off <<= 1) var += __shfl_xor(var, off);
      var *= (1.f / 64.f);
      float v = d * rsqrtf(var + LNEPS) * ln_g[round * Hd + u] + ln_b[round * Hd + u];
      hnew = fmaxf(v, 0.f);
    }
    __syncthreads();               // all reads of hcur done
    if (tid < 64) hcur[tid] = hnew;
    __syncthreads();
  }

  // ---- u/v precompute (threads 0..127)
  if (tid < 64) {
    const float* wr = W1 + tid * 133;          // cols 0..63 (h_i)
    float acc = b1[tid];
    #pragma unroll 8
    for (int k = 0; k < Hd; ++k) acc += hcur[k] * wr[k];
    uu[row * Hd + tid] = acc;
  } else if (tid < 128) {
    const int n = tid - 64;
    const float* wr = W1 + n * 133 + 64;       // cols 64..127 (h_j)
    float acc = 0.f;
    #pragma unroll 8
    for (int k = 0; k < Hd; ++k) acc += hcur[k] * wr[k];
    vt[n * NSEQ + row] = acc;
  }
}

// --------------------------------------------------------------------------
// Edge MLP: thread per edge. z1[64] lives in VGPRs; W1c/W2/W3/b2 have
// wave-uniform indices -> scalar-pipe loads, fmac v,s,v at VALU issue peak.
__global__ __launch_bounds__(256) void k_mlp(
    const float* __restrict__ ef,
    const float* __restrict__ u, const float* __restrict__ vt,
    const float* __restrict__ W1,
    const float* __restrict__ W2, const float* __restrict__ b2,
    const float* __restrict__ W3, const float* __restrict__ b3,
    float* __restrict__ out)
{
  const int idx = blockIdx.x * 256 + threadIdx.x;   // < 320000
  const int b   = idx / (Nd * Nd);
  const int rem = idx - b * Nd * Nd;
  const int i   = rem / Nd;
  const int jj  = rem - i * Nd;

  const float* e = ef + (((b * Wd + (Wd - 1)) * Nd + i) * Nd + jj) * Ed;
  float e5[Ed];
  #pragma unroll
  for (int q = 0; q < Ed; ++q) e5[q] = e[q];

  const float* ur = u + (b * Nd + i) * Hd;
  const int vcol = b * Nd + jj;

  float z1[64];
  #pragma unroll
  for (int k = 0; k < 64; ++k) {
    float acc = ur[k] + vt[k * NSEQ + vcol];
    const float* w1c = W1 + k * 133 + 128;      // uniform -> scalar loads
    #pragma unroll
    for (int q = 0; q < Ed; ++q) acc += e5[q] * w1c[q];
    z1[k] = fmaxf(acc, 0.f);
  }

  float logit = b3[0];
  #pragma unroll 4
  for (int o = 0; o < 32; ++o) {
    float a0 = b2[o], a1 = 0.f, a2 = 0.f, a3 = 0.f;
    const float* w2 = W2 + o * 64;              // uniform -> scalar loads
    #pragma unroll
    for (int k = 0; k < 64; k += 4) {
      a0 += w2[k]     * z1[k];
      a1 += w2[k + 1] * z1[k + 1];
      a2 += w2[k + 2] * z1[k + 2];
      a3 += w2[k + 3] * z1[k + 3];
    }
    float z2 = fmaxf((a0 + a1) + (a2 + a3), 0.f);
    logit += W3[o] * z2;
  }
  out[idx] = 1.f / (1.f + __expf(-logit));
}

// --------------------------------------------------------------------------
extern "C" void kernel_launch(void* const* d_in, const int* in_sizes, int n_in,
                              void* d_out, int out_size, void* d_ws, size_t ws_size,
                              hipStream_t stream) {
  (void)in_sizes; (void)n_in; (void)out_size; (void)ws_size;
  const float* nf   = (const float*)d_in[0];
  const float* ef   = (const float*)d_in[1];
  const float* adj  = (const float*)d_in[2];
  const float* Wih0 = (const float*)d_in[3];
  const float* Whh0 = (const float*)d_in[4];
  const float* bih0 = (const float*)d_in[5];
  const float* bhh0 = (const float*)d_in[6];
  const float* Wih1 = (const float*)d_in[7];
  const float* Whh1 = (const float*)d_in[8];
  const float* bih1 = (const float*)d_in[9];
  const float* bhh1 = (const float*)d_in[10];
  const float* gcnW = (const float*)d_in[11];
  const float* gcnB = (const float*)d_in[12];
  const float* epW  = (const float*)d_in[13];
  const float* epB  = (const float*)d_in[14];
  const float* lnG  = (const float*)d_in[15];
  const float* lnB  = (const float*)d_in[16];
  const float* W1   = (const float*)d_in[17];
  const float* b1   = (const float*)d_in[18];
  const float* W2   = (const float*)d_in[19];
  const float* b2   = (const float*)d_in[20];
  const float* W3   = (const float*)d_in[21];
  const float* b3   = (const float*)d_in[22];
  float* out = (float*)d_out;

  // Workspace layout (floats).
  float* ws  = (float*)d_ws;
  float* y0  = ws;                         // 1600*12*64 = 1,228,800
  float* G1  = y0  + 1228800;              // 19200*256  = 4,915,200
  float* Wt1 = G1  + 4915200;              // 64*256     = 16,384
  float* h0  = Wt1 + 16384;                // 1600*64    = 102,400
  float* uu  = h0  + 102400;               // 102,400
  float* vt  = uu  + 102400;               // 102,400

  k_prep  <<<64,        256, 0, stream>>>(Wih1, Wt1);
  k_lstm0 <<<NSEQ/SEQB, 256, 0, stream>>>(nf, Wih0, Whh0, bih0, bhh0, y0);
  k_xproj1<<<300,       256, 0, stream>>>(y0, Wt1, bih1, bhh1, G1);
  k_lstm1 <<<NSEQ/SEQB, 256, 0, stream>>>(G1, Whh1, h0);
  k_node  <<<1600,      256, 0, stream>>>(ef, adj, h0, gcnW, gcnB, epW, epB,
                                          lnG, lnB, W1, b1, uu, vt);
  k_mlp   <<<1250,      256, 0, stream>>>(ef, uu, vt, W1, W2, b2, W3, b3, out);
}

// Round 8
// 270.230 us; speedup vs baseline: 1.1788x; 1.1788x over previous
//
#include <hip/hip_runtime.h>
#include <math.h>

// ---------------------------------------------------------------------------
// TemporalGCN: 2-layer LSTM (per-node sequences) -> 2 GCN rounds -> edge MLP.
//
// R7 post-mortem: SEQB=4 halved FETCH_SIZE with ZERO time change -> weight
// re-fetch is NOT the bottleneck. New theory: every timestep had a
// global_store before the barrier; compiler emits s_waitcnt vmcnt(0) before
// s_barrier -> per-step ~200-900 cyc store-drain stall, barrier-aligned so
// occupancy can't hide it. Fits the invariant 59-80us across R2/R4/R5/R6/R7.
// R8: (1) lstm: NO global stores inside the t-loop (yreg[12], stored after);
//     (2) k_node: coalesced LDS staging of adj/ef rows + transposed weights
//         (gcn_W/ep_W/W1a/W1b column-major via k_prep).
// All FP accumulation orders preserved -> absmax 0.0 maintained.
// ---------------------------------------------------------------------------

#define Hd   64
#define Ed   5
#define Fd   6
#define Bd   8
#define Wd   12
#define Nd   200
#define NSEQ (Bd*Nd)        // 1600 sequences (b,n)
#define NG   (4*Hd)         // 256 gate rows
#define NEDGE (Bd*Nd*Nd)    // 320000 edges
#define LNEPS 1e-5f

__device__ __forceinline__ float sigm(float x) { return 1.0f / (1.0f + __expf(-x)); }
__device__ __forceinline__ float tanh_fast(float x) {
  float ax = fabsf(x);
  float t  = __expf(-2.0f * ax);
  float r  = (1.0f - t) / (1.0f + t);
  return copysignf(r, x);
}

// --------------------------------------------------------------------------
// Prep: Wt1 = Wih1^T (64x256); gcnWT[round][k][u]; epWT[round][e][u];
// W1aT[k][n] = W1[n][k]; W1bT[k][n] = W1[n][64+k]. Flat-index dispatch.
// Sizes: 16384 + 8192 + 640 + 4096 + 4096 = 33408 elements.
__global__ __launch_bounds__(256) void k_prep(
    const float* __restrict__ Wih1, const float* __restrict__ gcn_W,
    const float* __restrict__ ep_W, const float* __restrict__ W1,
    float* __restrict__ Wt1, float* __restrict__ gcnWT,
    float* __restrict__ epWT, float* __restrict__ W1aT,
    float* __restrict__ W1bT)
{
  int idx = blockIdx.x * 256 + threadIdx.x;
  if (idx < 16384) {                       // Wt1[k][j] = Wih1[j][k]
    int k = idx >> 8, j = idx & 255;
    Wt1[idx] = Wih1[j * Hd + k];
  } else if (idx < 24576) {                // gcnWT[r][k][u] = gcn_W[r][u][k]
    int r0 = idx - 16384;
    int round = r0 >> 12, rem = r0 & 4095;
    int k = rem >> 6, u = rem & 63;
    gcnWT[r0] = gcn_W[round * 4096 + u * 64 + k];
  } else if (idx < 25216) {                // epWT[r][e][u] = ep_W[r][u][e]
    int r0 = idx - 24576;
    int round = r0 / 320, rem = r0 % 320;
    int e = rem >> 6, u = rem & 63;
    epWT[r0] = ep_W[round * 320 + u * Ed + e];
  } else if (idx < 29312) {                // W1aT[k][n] = W1[n][k]
    int r0 = idx - 25216;
    int k = r0 >> 6, n = r0 & 63;
    W1aT[r0] = W1[n * 133 + k];
  } else if (idx < 33408) {                // W1bT[k][n] = W1[n][64+k]
    int r0 = idx - 29312;
    int k = r0 >> 6, n = r0 & 63;
    W1bT[r0] = W1[n * 133 + 64 + k];
  }
}

// --------------------------------------------------------------------------
// LSTM layer 0. 1600 blocks x 256 threads; block owns ONE sequence.
// Thread j = gate row j. ONE barrier/step (R6-proven redundant update with
// double-buffered gate_sh). NO global stores inside the t-loop: h history
// kept in yreg[12], stored coalesced by wave 0 after the loop.
__global__ __launch_bounds__(256, 3) void k_lstm0(
    const float* __restrict__ nf,                       // (B,W,N,F)
    const float* __restrict__ Wih0, const float* __restrict__ Whh0,
    const float* __restrict__ bih0, const float* __restrict__ bhh0,
    float* __restrict__ y0)                             // (NSEQ, W, H)
{
  __shared__ float x_sh[Wd * Fd];     // 72
  __shared__ float h_sh[Hd];          // 64
  __shared__ float gate_sh[2][NG];    // double-buffered post-activation gates

  const int tid = threadIdx.x;
  const int seq = blockIdx.x;
  const int b = seq / Nd, n = seq % Nd;
  const int u = tid & 63;

  if (tid < Wd * Fd) {
    int t = tid / Fd, f = tid % Fd;
    x_sh[tid] = nf[((b * Wd + t) * Nd + n) * Fd + f];
  }
  h_sh[u] = 0.f;                      // 4x dup identical-value write

  const int j = tid;
  float4 wh[16];
  const float4* wrow = (const float4*)(Whh0 + j * Hd);
  #pragma unroll
  for (int q = 0; q < 16; ++q) wh[q] = wrow[q];
  float wx[Fd];
  #pragma unroll
  for (int f = 0; f < Fd; ++f) wx[f] = Wih0[j * Fd + f];
  const float bias = bih0[j] + bhh0[j];
  const int jt = j >> 6;              // 0=i,1=f,2=g,3=o (wave-uniform)

  float c = 0.f;                      // cell state for unit u (per-wave copy)
  float yreg[Wd];                     // h history, stored after the loop
  __syncthreads();

  for (int t = 0; t < Wd; ++t) {
    const float* xp = x_sh + t * Fd;
    float a0 = bias, a1 = 0.f, a2 = 0.f, a3 = 0.f;
    #pragma unroll
    for (int f = 0; f < Fd; ++f) a1 += xp[f] * wx[f];
    const float4* h4 = (const float4*)h_sh;
    #pragma unroll
    for (int q = 0; q < 16; ++q) {
      float4 hv = h4[q];
      float d = hv.x * wh[q].x + hv.y * wh[q].y + hv.z * wh[q].z + hv.w * wh[q].w;
      if ((q & 3) == 0) a0 += d; else if ((q & 3) == 1) a1 += d;
      else if ((q & 3) == 2) a2 += d; else a3 += d;
    }
    float acc = (a0 + a1) + (a2 + a3);
    gate_sh[t & 1][j] = (jt == 2) ? tanh_fast(acc) : sigm(acc);
    __syncthreads();                  // the ONLY barrier per step (no vm ops pending)
    const float* gb = gate_sh[t & 1];
    float iv = gb[u];
    float fv = gb[64 + u];
    float gv = gb[128 + u];
    float ov = gb[192 + u];
    c = fv * c + iv * gv;
    float h = ov * tanh_fast(c);
    h_sh[u] = h;                      // dup identical-value writes: benign
    yreg[t] = h;
  }
  if (tid < Hd) {
    #pragma unroll
    for (int t = 0; t < Wd; ++t)
      y0[seq * (Wd * Hd) + t * Hd + u] = yreg[t];   // coalesced 256B stores
  }
}

// --------------------------------------------------------------------------
// G1 = y0 @ Wih1.T + (bih1+bhh1): (19200 x 64) @ (64 x 256).
// 300 blocks x 256 thr; lane = row, wave = 64-col slab (wave-uniform cols ->
// weights via SCALAR loads; VALU-bound). Output transposed through a 2-tile
// osh in two passes (LDS total 49.9 KB < 64 KB static limit).
__global__ __launch_bounds__(256) void k_xproj1(
    const float* __restrict__ y0,    // rows = seq*12+t
    const float* __restrict__ Wt1,   // (64,256) transposed Wih1
    const float* __restrict__ bih1, const float* __restrict__ bhh1,
    float* __restrict__ G1)          // (19200, 256)
{
  __shared__ float ysh[64 * 65];        // [r][k] pad-65: conflict-free
  __shared__ float osh[2 * 64 * 65];    // two 64x64 out tiles, pad-65

  const int tid  = threadIdx.x;
  const int row0 = blockIdx.x * 64;
  for (int idx = tid; idx < 64 * 64; idx += 256) {
    int r = idx >> 6, k = idx & 63;
    ysh[r * 65 + k] = y0[(row0 + r) * Hd + k];
  }
  __syncthreads();

  const int w = __builtin_amdgcn_readfirstlane(tid >> 6);  // force uniform
  const int r = tid & 63;
  float acc[64];
  #pragma unroll
  for (int c = 0; c < 64; ++c) acc[c] = 0.f;

  const float* wbase = Wt1 + (w << 6);
  #pragma unroll 2
  for (int k = 0; k < 64; ++k) {
    float yv = ysh[r * 65 + k];
    const float* wk = wbase + k * NG;    // uniform address -> s_load
    #pragma unroll
    for (int c = 0; c < 64; ++c) acc[c] = fmaf(yv, wk[c], acc[c]);
  }
  #pragma unroll
  for (int c = 0; c < 64; ++c) acc[c] += bih1[(w << 6) + c] + bhh1[(w << 6) + c];

  // Two passes: waves {0,1} then {2,3} dump 64x64 tiles; everyone stores.
  #pragma unroll
  for (int p = 0; p < 2; ++p) {
    __syncthreads();
    if ((w >> 1) == p) {
      float* orow = osh + ((w & 1) * 64 + r) * 65;
      #pragma unroll
      for (int c = 0; c < 64; ++c) orow[c] = acc[c];  // stride-65: no conflict
    }
    __syncthreads();
    for (int idx = tid; idx < 2 * 64 * 64; idx += 256) {
      int c  = idx & 127;              // col within this 128-col slab
      int rr = idx >> 7;               // row 0..63
      G1[(row0 + rr) * NG + p * 128 + c] =
          osh[((c >> 6) * 64 + rr) * 65 + (c & 63)];   // lanes stride-1: free
    }
  }
}

// --------------------------------------------------------------------------
// LSTM layer 1 recurrence (K=64; input proj precomputed in G1). 1600 blocks
// x 256 threads, same single-barrier structure as k_lstm0. G1 prefetched one
// timestep ahead; final h stored after the loop (no in-loop global stores).
__global__ __launch_bounds__(256, 3) void k_lstm1(
    const float* __restrict__ G1,
    const float* __restrict__ Whh1,
    float* __restrict__ hout)        // (NSEQ, H)
{
  __shared__ float h_sh[Hd];
  __shared__ float gate_sh[2][NG];

  const int tid = threadIdx.x;
  const int seq = blockIdx.x;
  const int u = tid & 63;
  h_sh[u] = 0.f;

  const int j = tid;
  float4 wh[16];
  const float4* wrow = (const float4*)(Whh1 + j * Hd);
  #pragma unroll
  for (int q = 0; q < 16; ++q) wh[q] = wrow[q];
  const int jt = j >> 6;
  float c = 0.f;
  float hlast = 0.f;

  float g_cur = G1[(seq * Wd + 0) * NG + j];   // prefetch t=0
  __syncthreads();

  for (int t = 0; t < Wd; ++t) {
    float g_next = (t + 1 < Wd) ? G1[(seq * Wd + t + 1) * NG + j] : 0.f;
    float a0 = g_cur;                          // bias folded into G1
    float a1 = 0.f, a2 = 0.f, a3 = 0.f;
    const float4* h4 = (const float4*)h_sh;
    #pragma unroll
    for (int q = 0; q < 16; ++q) {
      float4 hv = h4[q];
      float d = hv.x * wh[q].x + hv.y * wh[q].y + hv.z * wh[q].z + hv.w * wh[q].w;
      if ((q & 3) == 0) a0 += d; else if ((q & 3) == 1) a1 += d;
      else if ((q & 3) == 2) a2 += d; else a3 += d;
    }
    float acc = (a0 + a1) + (a2 + a3);
    gate_sh[t & 1][j] = (jt == 2) ? tanh_fast(acc) : sigm(acc);
    __syncthreads();                  // the ONLY barrier per step
    const float* gb = gate_sh[t & 1];
    float iv = gb[u];
    float fv = gb[64 + u];
    float gv = gb[128 + u];
    float ov = gb[192 + u];
    c = fv * c + iv * gv;
    float h = ov * tanh_fast(c);
    h_sh[u] = h;
    hlast = h;
    g_cur = g_next;
  }
  if (tid < Hd) hout[seq * Hd + u] = hlast;
}

// --------------------------------------------------------------------------
// Fused per-row node pipeline: wsum -> GCN r0 -> GCN r1 -> u/v precompute.
// One block per row (b,i); 256 threads. adj/ef rows staged into LDS with
// COALESCED loads; all weight reads coalesced via the k_prep transposes.
// Accumulation orders identical to R7 (same values, new addressing).
__global__ __launch_bounds__(256) void k_node(
    const float* __restrict__ ef,    const float* __restrict__ adj,
    const float* __restrict__ h0,
    const float* __restrict__ gcnWT, const float* __restrict__ gcn_b,
    const float* __restrict__ epWT,  const float* __restrict__ ep_b,
    const float* __restrict__ ln_g,  const float* __restrict__ ln_b,
    const float* __restrict__ W1aT,  const float* __restrict__ W1bT,
    const float* __restrict__ b1,
    float* __restrict__ uu, float* __restrict__ vt)
{
  __shared__ float ef_sh[Nd * Ed];   // 1000: edge_last row (coalesced stage)
  __shared__ float adj_sh[Nd];       // 200
  __shared__ float red[4][6];
  __shared__ float w6[6];
  __shared__ float hcur[Hd];

  const int row = blockIdx.x;      // b*200+i
  const int b = row / Nd, i = row % Nd;
  const int tid = threadIdx.x;

  const float* efrow = ef + (size_t)(((b * Wd + (Wd - 1)) * Nd + i)) * (Nd * Ed);
  for (int idx = tid; idx < Nd * Ed; idx += 256) ef_sh[idx] = efrow[idx];
  const float* adjrow = adj + (b * Nd + i) * Nd;
  if (tid < Nd) adj_sh[tid] = adjrow[tid];
  if (tid < Hd) hcur[tid] = h0[row * Hd + tid];
  __syncthreads();

  // ---- wsum: p[e] = sum_j adj*edge[e], p[5] = sum_j adj (order as before)
  float p[6] = {0.f, 0.f, 0.f, 0.f, 0.f, 0.f};
  if (tid < Nd) {
    float a = adj_sh[tid];
    p[5] = a;
    #pragma unroll
    for (int k = 0; k < Ed; ++k) p[k] = a * ef_sh[tid * Ed + k];
  }
  #pragma unroll
  for (int k = 0; k < 6; ++k) {
    float v = p[k];
    for (int off = 32; off > 0; off >>= 1) v += __shfl_down(v, off);
    p[k] = v;
  }
  if ((tid & 63) == 0) {
    #pragma unroll
    for (int k = 0; k < 6; ++k) red[tid >> 6][k] = p[k];
  }
  __syncthreads();
  if (tid < 6)
    w6[tid] = red[0][tid] + red[1][tid] + red[2][tid] + red[3][tid];
  __syncthreads();

  // ---- 2 GCN rounds (wave 0; coalesced transposed-weight reads)
  const int u = tid & 63;
  #pragma unroll
  for (int round = 0; round < 2; ++round) {
    float hnew = 0.f;
    if (tid < 64) {
      const float* gwT = gcnWT + round * 4096;   // [k][u]
      const float* ewT = epWT  + round * 320;    // [e][u]
      float acc = gcn_b[round * Hd + u] + w6[5] * ep_b[round * Hd + u];
      #pragma unroll
      for (int e = 0; e < Ed; ++e) acc += w6[e] * ewT[e * 64 + u];
      #pragma unroll 8
      for (int k = 0; k < Hd; ++k) acc += hcur[k] * gwT[k * 64 + u];

      float mu = acc;
      #pragma unroll
      for (int off = 1; off < 64; off <<= 1) mu += __shfl_xor(mu, off);
      mu *= (1.f / 64.f);
      float d = acc - mu;
      float var = d * d;
      #pragma unroll
      for (int off = 1; off < 64; off <<= 1) var += __shfl_xor(var, off);
      var *= (1.f / 64.f);
      float v = d * rsqrtf(var + LNEPS) * ln_g[round * Hd + u] + ln_b[round * Hd + u];
      hnew = fmaxf(v, 0.f);
    }
    __syncthreads();               // all reads of hcur done
    if (tid < 64) hcur[tid] = hnew;
    __syncthreads();
  }

  // ---- u/v precompute (threads 0..127; coalesced transposed W1 reads)
  if (tid < 64) {
    float acc = b1[tid];
    #pragma unroll 8
    for (int k = 0; k < Hd; ++k) acc += hcur[k] * W1aT[k * 64 + tid];
    uu[row * Hd + tid] = acc;
  } else if (tid < 128) {
    const int n = tid - 64;
    float acc = 0.f;
    #pragma unroll 8
    for (int k = 0; k < Hd; ++k) acc += hcur[k] * W1bT[k * 64 + n];
    vt[n * NSEQ + row] = acc;
  }
}

// --------------------------------------------------------------------------
// Edge MLP: thread per edge. z1[64] lives in VGPRs; W1c/W2/W3/b2 have
// wave-uniform indices -> scalar-pipe loads, fmac v,s,v at VALU issue peak.
__global__ __launch_bounds__(256) void k_mlp(
    const float* __restrict__ ef,
    const float* __restrict__ u, const float* __restrict__ vt,
    const float* __restrict__ W1,
    const float* __restrict__ W2, const float* __restrict__ b2,
    const float* __restrict__ W3, const float* __restrict__ b3,
    float* __restrict__ out)
{
  const int idx = blockIdx.x * 256 + threadIdx.x;   // < 320000
  const int b   = idx / (Nd * Nd);
  const int rem = idx - b * Nd * Nd;
  const int i   = rem / Nd;
  const int jj  = rem - i * Nd;

  const float* e = ef + (((b * Wd + (Wd - 1)) * Nd + i) * Nd + jj) * Ed;
  float e5[Ed];
  #pragma unroll
  for (int q = 0; q < Ed; ++q) e5[q] = e[q];

  const float* ur = u + (b * Nd + i) * Hd;
  const int vcol = b * Nd + jj;

  float z1[64];
  #pragma unroll
  for (int k = 0; k < 64; ++k) {
    float acc = ur[k] + vt[k * NSEQ + vcol];
    const float* w1c = W1 + k * 133 + 128;      // uniform -> scalar loads
    #pragma unroll
    for (int q = 0; q < Ed; ++q) acc += e5[q] * w1c[q];
    z1[k] = fmaxf(acc, 0.f);
  }

  float logit = b3[0];
  #pragma unroll 4
  for (int o = 0; o < 32; ++o) {
    float a0 = b2[o], a1 = 0.f, a2 = 0.f, a3 = 0.f;
    const float* w2 = W2 + o * 64;              // uniform -> scalar loads
    #pragma unroll
    for (int k = 0; k < 64; k += 4) {
      a0 += w2[k]     * z1[k];
      a1 += w2[k + 1] * z1[k + 1];
      a2 += w2[k + 2] * z1[k + 2];
      a3 += w2[k + 3] * z1[k + 3];
    }
    float z2 = fmaxf((a0 + a1) + (a2 + a3), 0.f);
    logit += W3[o] * z2;
  }
  out[idx] = 1.f / (1.f + __expf(-logit));
}

// --------------------------------------------------------------------------
extern "C" void kernel_launch(void* const* d_in, const int* in_sizes, int n_in,
                              void* d_out, int out_size, void* d_ws, size_t ws_size,
                              hipStream_t stream) {
  (void)in_sizes; (void)n_in; (void)out_size; (void)ws_size;
  const float* nf   = (const float*)d_in[0];
  const float* ef   = (const float*)d_in[1];
  const float* adj  = (const float*)d_in[2];
  const float* Wih0 = (const float*)d_in[3];
  const float* Whh0 = (const float*)d_in[4];
  const float* bih0 = (const float*)d_in[5];
  const float* bhh0 = (const float*)d_in[6];
  const float* Wih1 = (const float*)d_in[7];
  const float* Whh1 = (const float*)d_in[8];
  const float* bih1 = (const float*)d_in[9];
  const float* bhh1 = (const float*)d_in[10];
  const float* gcnW = (const float*)d_in[11];
  const float* gcnB = (const float*)d_in[12];
  const float* epW  = (const float*)d_in[13];
  const float* epB  = (const float*)d_in[14];
  const float* lnG  = (const float*)d_in[15];
  const float* lnB  = (const float*)d_in[16];
  const float* W1   = (const float*)d_in[17];
  const float* b1   = (const float*)d_in[18];
  const float* W2   = (const float*)d_in[19];
  const float* b2   = (const float*)d_in[20];
  const float* W3   = (const float*)d_in[21];
  const float* b3   = (const float*)d_in[22];
  float* out = (float*)d_out;

  // Workspace layout (floats).
  float* ws   = (float*)d_ws;
  float* y0   = ws;                        // 1600*12*64 = 1,228,800
  float* G1   = y0   + 1228800;            // 19200*256  = 4,915,200
  float* Wt1  = G1   + 4915200;            // 16,384
  float* h0   = Wt1  + 16384;              // 102,400
  float* uu   = h0   + 102400;             // 102,400
  float* vt   = uu   + 102400;             // 102,400
  float* gWT  = vt   + 102400;             // 8,192
  float* eWT  = gWT  + 8192;               // 640
  float* W1aT = eWT  + 640;                // 4,096
  float* W1bT = W1aT + 4096;               // 4,096

  k_prep  <<<131,  256, 0, stream>>>(Wih1, gcnW, epW, W1,
                                     Wt1, gWT, eWT, W1aT, W1bT);
  k_lstm0 <<<NSEQ, 256, 0, stream>>>(nf, Wih0, Whh0, bih0, bhh0, y0);
  k_xproj1<<<300,  256, 0, stream>>>(y0, Wt1, bih1, bhh1, G1);
  k_lstm1 <<<NSEQ, 256, 0, stream>>>(G1, Whh1, h0);
  k_node  <<<1600, 256, 0, stream>>>(ef, adj, h0, gWT, gcnB, eWT, epB,
                                     lnG, lnB, W1aT, W1bT, b1, uu, vt);
  k_mlp   <<<1250, 256, 0, stream>>>(ef, uu, vt, W1, W2, b2, W3, b3, out);
}